// Round 16
// baseline (964.103 us; speedup 1.0000x reference)
//
#include <hip/hip_runtime.h>
#include <hip/hip_bf16.h>

#define DD 8
#define SS 64
#define HH 128
#define OUTD 8
#define TT 2049
#define BB 32
#define WINW 16
#define NWIN 128
#define PP 28
#define DSTR 68            // Vl d-stride (floats): 4-bank shift per d
#define CSTR 548           // Vl chain stride = 8*68 + 4

typedef __attribute__((ext_vector_type(8))) short short8v;
typedef __attribute__((ext_vector_type(4))) float f32x4;

__device__ __forceinline__ float softplus_f(float x){
    return fmaxf(x, 0.f) + __logf(1.f + __expf(-fabsf(x)));
}
__device__ __forceinline__ float tanh_f(float x){
    float e = __expf(2.f * x);
    return 1.f - 2.f / (e + 1.f);
}
__device__ __forceinline__ void sp_sig(float x, float& sp, float& sg){
    float t = __expf(-fabsf(x));
    float r = 1.f / (1.f + t);
    sg = x > 0.f ? r : 1.f - r;
    sp = fmaxf(x, 0.f) - __logf(r);
}
__device__ __forceinline__ unsigned short f2bf(float f){
    return __builtin_bit_cast(unsigned short, __float2bfloat16(f));
}
__device__ __forceinline__ unsigned pk2(float a, float b){
    unsigned lo = (unsigned)__builtin_bit_cast(unsigned short, __float2bfloat16(a));
    unsigned hi = (unsigned)__builtin_bit_cast(unsigned short, __float2bfloat16(b));
    return lo | (hi << 16);
}

// ---------------- signatures: s1 (B,NWIN,D), s2 (B,NWIN,P) ----------------
__global__ void sig_kernel(const float* __restrict__ x,
                           float* __restrict__ s1o, float* __restrict__ s2o){
    int w = blockIdx.x * blockDim.x + threadIdx.x;
    if (w >= BB * NWIN) return;
    int b = w >> 7, n = w & (NWIN - 1);
    const float* xp = x + ((size_t)b * TT + (size_t)n * WINW) * DD;
    float prev[DD], cum[DD], s1v[DD], M[DD][DD];
    #pragma unroll
    for (int i = 0; i < DD; ++i){
        cum[i] = 0.f; s1v[i] = 0.f;
        #pragma unroll
        for (int j = 0; j < DD; ++j) M[i][j] = 0.f;
    }
    #pragma unroll
    for (int i = 0; i < DD; ++i) prev[i] = xp[i];
    for (int t = 0; t < WINW; ++t){
        float cur[DD], del[DD];
        #pragma unroll
        for (int i = 0; i < DD; ++i) cur[i] = xp[(t + 1) * DD + i];
        #pragma unroll
        for (int i = 0; i < DD; ++i) del[i] = cur[i] - prev[i];
        #pragma unroll
        for (int i = 0; i < DD; ++i){
            #pragma unroll
            for (int j = 0; j < DD; ++j) M[i][j] += cum[i] * del[j];
        }
        #pragma unroll
        for (int i = 0; i < DD; ++i){ cum[i] += del[i]; s1v[i] += del[i]; prev[i] = cur[i]; }
    }
    #pragma unroll
    for (int i = 0; i < DD; ++i) s1o[(size_t)w * DD + i] = s1v[i];
    int p = 0;
    #pragma unroll
    for (int i = 0; i < DD; ++i){
        #pragma unroll
        for (int j = i + 1; j < DD; ++j){ s2o[(size_t)w * PP + p] = 0.5f * (M[i][j] - M[j][i]); ++p; }
    }
}

// image position (shorts): k-row k, col nn of a [K/32][64][8] B-image
#define BPOS(k, nn) ((((k) >> 5) * 64 + (((k) >> 3) & 3) * 16 + (nn)) * 8 + ((k) & 7))

// ---------------- main scan: 4 chains per 512-thread block, 8 waves, 7 phases ----------------
__global__ __launch_bounds__(512, 2) void scan_kernel(
    const float* __restrict__ x,
    const float* __restrict__ Wi0, const float* __restrict__ bi0,
    const float* __restrict__ Wi1, const float* __restrict__ bi1,
    const float* __restrict__ Wi2, const float* __restrict__ bi2,
    const float* __restrict__ Wv0, const float* __restrict__ bv0,
    const float* __restrict__ Wv1, const float* __restrict__ bv1,
    const float* __restrict__ Wv2, const float* __restrict__ bv2,
    const float* __restrict__ Wr,  const float* __restrict__ br,
    const float* __restrict__ s1g, const float* __restrict__ s2g,
    float* __restrict__ out)
{
    const int tid = threadIdx.x;
    const int w   = tid >> 6;   // wave 0..7
    const int l   = tid & 63;
    const int lg  = l >> 4;
    const int ln  = l & 15;
    const int b0  = blockIdx.x * 4;

    __shared__ __align__(16) short BpH[2 * 64 * 8];       // h:  cols 0-3 = chains
    __shared__ __align__(16) short Bp0[4 * 64 * 8];       // z0: cols 0-3
    __shared__ __align__(16) short Bp1[4 * 64 * 8];       // z1: chain c -> cols 4c..4c+3 (dup)
    __shared__ __align__(16) short Bp7[2][2 * 64 * 8];    // u:  image c>>1, col (c&1)*8+d
    __shared__ __align__(16) short Bp8[2][4 * 64 * 8];    // t0: image p, col (c-2p)*8+d
    __shared__ __align__(16) short Bp9[2][4 * 64 * 8];    // q:  image d>>2, col (d&3)*4+c
    __shared__ __align__(16) float s0p[4][HH], s1p[4][HH];
    __shared__ __align__(16) float Vl[4 * CSTR];          // [c*CSTR + d*DSTR + s]
    __shared__ __align__(16) float hfb[4][2][SS];
    __shared__ __align__(16) float bv0L[HH], bv1L[HH], bv2L[512];
    __shared__ __align__(16) float WrL[OUTD * SS];
    __shared__ float brL[OUTD];
    __shared__ __align__(16) float sAll[4][NWIN * DD];    // 16 KB
    __shared__ __align__(16) float bAll[4][NWIN * PP];    // 56 KB
    __shared__ __align__(16) float outC[4][32][OUTD];     // 4 KB
    __shared__ __align__(16) float Cexp[2][4][DD][12];    // double-buffered

    // -------- prologue: reg A-fragments --------
    short8v a0f[2], a1f[4];
    short8v a2p0[4], a2p1[4], a2p2[4], a2p3[4];   // W2 PERMUTED rows' = 64w+16t+ln
    #pragma unroll
    for (int ks = 0; ks < 2; ++ks){
        const float* p = Wv0 + (size_t)(w * 16 + ln) * SS + ks * 32 + lg * 8;
        short8v f;
        #pragma unroll
        for (int j = 0; j < 8; ++j) f[j] = (short)f2bf(p[j]);
        a0f[ks] = f;
    }
    #pragma unroll
    for (int ks = 0; ks < 4; ++ks){
        const float* p = Wv1 + (size_t)(w * 16 + ln) * HH + ks * 32 + lg * 8;
        short8v f;
        #pragma unroll
        for (int j = 0; j < 8; ++j) f[j] = (short)f2bf(p[j]);
        a1f[ks] = f;
    }
    {
        const int dP = ln & 7;
        #pragma unroll
        for (int t = 0; t < 4; ++t){
            const int sP = 8 * w + 2 * t + (ln >> 3);
            const float* p = Wv2 + (size_t)(dP * 64 + sP) * HH;
            #pragma unroll
            for (int ks = 0; ks < 4; ++ks){
                const float* pp = p + ks * 32 + lg * 8;
                short8v f;
                #pragma unroll
                for (int j = 0; j < 8; ++j) f[j] = (short)f2bf(pp[j]);
                if (t == 0) a2p0[ks] = f;
                else if (t == 1) a2p1[ks] = f;
                else if (t == 2) a2p2[ks] = f;
                else a2p3[ks] = f;
            }
        }
    }
    if (tid < HH){ bv0L[tid] = bv0[tid]; bv1L[tid] = bv1[tid]; }
    bv2L[tid] = bv2[tid];
    WrL[tid]  = Wr[tid];
    if (tid < OUTD) brL[tid] = br[tid];
    {
        float* sF = &sAll[0][0];
        for (int i = tid; i < 4 * NWIN * DD; i += 512){
            int c = i >> 10;
            sF[i] = s1g[(size_t)(b0 + c) * (NWIN * DD) + (i & 1023)];
        }
        float* bF = &bAll[0][0];
        for (int i = tid; i < 4 * NWIN * PP; i += 512){
            int c = i / (NWIN * PP);
            bF[i] = s2g[(size_t)(b0 + c) * (NWIN * PP) + (i - c * (NWIN * PP))];
        }
        for (int i = tid; i < 2 * 64 * 8; i += 512) BpH[i] = 0;
        for (int i = tid; i < 4 * 64 * 8; i += 512){ Bp0[i] = 0; Bp1[i] = 0; }
    }
    __syncthreads();

    // -------- initial MLP (f32) for 4 chains + Cexp[0] for step 0 --------
    {
        int c4 = tid >> 7, r = tid & 127;
        float acc = bi0[r];
        const float* x0 = x + (size_t)(b0 + c4) * TT * DD;
        #pragma unroll
        for (int k = 0; k < DD; ++k) acc += Wi0[r * DD + k] * x0[k];
        s0p[c4][r] = softplus_f(acc);
    }
    if (tid < 256){
        int cc = tid >> 6, dd = (tid >> 3) & 7, ee = tid & 7;
        const float* bco = &bAll[cc][0];
        float cv = 0.f;
        if (ee < dd)      cv =  bco[((ee * (15 - ee)) >> 1) + dd - ee - 1];
        else if (ee > dd) cv = -bco[((dd * (15 - dd)) >> 1) + ee - dd - 1];
        Cexp[0][cc][dd][ee] = cv;
    }
    __syncthreads();
    {
        int c4 = tid >> 7, r = tid & 127;
        float acc = bi1[r];
        const f32x4* wv = (const f32x4*)(Wi1 + (size_t)r * HH);
        const f32x4* zv = (const f32x4*)&s0p[c4][0];
        #pragma unroll 8
        for (int k = 0; k < 32; ++k){
            f32x4 a = wv[k], z = zv[k];
            acc += a.x * z.x + a.y * z.y + a.z * z.z + a.w * z.w;
        }
        s1p[c4][r] = softplus_f(acc);
    }
    __syncthreads();
    if (tid < 256){
        int c4 = tid >> 6, s = tid & 63;
        float acc = bi2[s];
        const f32x4* wv = (const f32x4*)(Wi2 + (size_t)s * HH);
        const f32x4* zv = (const f32x4*)&s1p[c4][0];
        #pragma unroll 8
        for (int k = 0; k < 32; ++k){
            f32x4 a = wv[k], z = zv[k];
            acc += a.x * z.x + a.y * z.y + a.z * z.z + a.w * z.w;
        }
        hfb[c4][0][s] = acc;
        BpH[BPOS(s, c4)] = (short)f2bf(acc);
    }
    __syncthreads();

    const f32x4 zero4 = {0.f, 0.f, 0.f, 0.f};
    const int rb = w * 16 + lg * 4;

    // -------- scan: 7 phases/step --------
    for (int n = 0; n < NWIN; ++n){
        const int cur = n & 1;
        // ---- S1: z0 = sp(W0 @ h), cols 0-3 ----
        {
            f32x4 acc = zero4;
            acc = __builtin_amdgcn_mfma_f32_16x16x32_bf16(a0f[0], *(const short8v*)&BpH[(0 * 64 + l) * 8], acc, 0, 0, 0);
            acc = __builtin_amdgcn_mfma_f32_16x16x32_bf16(a0f[1], *(const short8v*)&BpH[(1 * 64 + l) * 8], acc, 0, 0, 0);
            if (ln < 4){
                int c = ln;
                f32x4 bv = *(const f32x4*)&bv0L[rb];
                float z[4], sgv[4];
                #pragma unroll
                for (int r = 0; r < 4; ++r){
                    float zz, gg;
                    sp_sig(acc[r] + bv[r], zz, gg);
                    z[r] = zz; sgv[r] = gg;
                }
                f32x4 sg = {sgv[0], sgv[1], sgv[2], sgv[3]};
                *(f32x4*)&s0p[c][rb] = sg;
                uint2 pk; pk.x = pk2(z[0], z[1]); pk.y = pk2(z[2], z[3]);
                *(uint2*)&Bp0[BPOS(rb, c)] = pk;
            }
        }
        __syncthreads();

        // ---- S3: z1 = sp(W1 @ z0); chain c -> Bp1 cols 4c..4c+3 (dup) ----
        {
            f32x4 acc = zero4;
            #pragma unroll
            for (int ks = 0; ks < 4; ++ks)
                acc = __builtin_amdgcn_mfma_f32_16x16x32_bf16(a1f[ks], *(const short8v*)&Bp0[(ks * 64 + l) * 8], acc, 0, 0, 0);
            if (ln < 4){
                int c = ln;
                f32x4 bv = *(const f32x4*)&bv1L[rb];
                float z[4], sgv[4];
                #pragma unroll
                for (int r = 0; r < 4; ++r){
                    float zz, gg;
                    sp_sig(acc[r] + bv[r], zz, gg);
                    z[r] = zz; sgv[r] = gg;
                }
                f32x4 sg = {sgv[0], sgv[1], sgv[2], sgv[3]};
                *(f32x4*)&s1p[c][rb] = sg;
                uint2 pk; pk.x = pk2(z[0], z[1]); pk.y = pk2(z[2], z[3]);
                #pragma unroll
                for (int cc = 0; cc < 4; ++cc) *(uint2*)&Bp1[BPOS(rb, c * 4 + cc)] = pk;
            }
        }
        __syncthreads();

        // ---- S4: V = tanh(W2P @ z1 + bv2), permuted rows; all lanes epilogue ----
        {
            short8v bf[4];
            #pragma unroll
            for (int ks = 0; ks < 4; ++ks) bf[ks] = *(const short8v*)&Bp1[(ks * 64 + l) * 8];
            f32x4 acc0 = zero4, acc1 = zero4, acc2 = zero4, acc3 = zero4;
            #pragma unroll
            for (int ks = 0; ks < 4; ++ks){
                acc0 = __builtin_amdgcn_mfma_f32_16x16x32_bf16(a2p0[ks], bf[ks], acc0, 0, 0, 0);
                acc1 = __builtin_amdgcn_mfma_f32_16x16x32_bf16(a2p1[ks], bf[ks], acc1, 0, 0, 0);
                acc2 = __builtin_amdgcn_mfma_f32_16x16x32_bf16(a2p2[ks], bf[ks], acc2, 0, 0, 0);
                acc3 = __builtin_amdgcn_mfma_f32_16x16x32_bf16(a2p3[ks], bf[ks], acc3, 0, 0, 0);
            }
            // lane: c = ln>>2, r_sel = ln&3, d = (lg&1)*4+r_sel, b = lg>>1
            {
                int c = ln >> 2, rs = ln & 3;
                int d = (lg & 1) * 4 + rs, b = lg >> 1;
                #pragma unroll
                for (int t = 0; t < 4; ++t){
                    int s = 8 * w + 2 * t + b;
                    float av = (t == 0) ? acc0[rs] : (t == 1) ? acc1[rs] : (t == 2) ? acc2[rs] : acc3[rs];
                    float v = tanh_f(av + bv2L[d * 64 + s]);
                    Vl[c * CSTR + d * DSTR + s] = v;
                }
            }
        }
        __syncthreads();

        // ---- U (waves 0-3): u-mix | (waves 4-5): Cexp(n+1) | (waves 6-7): readout ----
        {
            if (tid < 256){
                int c = tid >> 6, d = (tid >> 3) & 7, s0 = (tid & 7) * 8;
                f32x4 cm0 = *(const f32x4*)&Cexp[cur][c][d][0];
                f32x4 cm1 = *(const f32x4*)&Cexp[cur][c][d][4];
                #pragma unroll
                for (int qq = 0; qq < 2; ++qq){
                    int sv = s0 + qq * 4;
                    f32x4 acc = zero4;
                    #pragma unroll
                    for (int e = 0; e < 8; ++e){
                        float ce = (e < 4) ? cm0[e] : cm1[e - 4];
                        f32x4 v4 = *(const f32x4*)&Vl[c * CSTR + e * DSTR + sv];
                        acc.x += ce * v4.x; acc.y += ce * v4.y;
                        acc.z += ce * v4.z; acc.w += ce * v4.w;
                    }
                    uint2 pk; pk.x = pk2(acc.x, acc.y); pk.y = pk2(acc.z, acc.w);
                    *(uint2*)&Bp7[c >> 1][BPOS(sv, (c & 1) * 8 + d)] = pk;
                }
            } else if (tid < 384){
                int idx = tid - 256;
                int cc = idx >> 5, dd = (idx >> 2) & 7, ep = idx & 3;
                int nn = (n + 1 < NWIN) ? n + 1 : NWIN - 1;
                const float* bco = &bAll[cc][nn * PP];
                #pragma unroll
                for (int h2 = 0; h2 < 2; ++h2){
                    int ee = ep + h2 * 4;
                    float cv = 0.f;
                    if (ee < dd)      cv =  bco[((ee * (15 - ee)) >> 1) + dd - ee - 1];
                    else if (ee > dd) cv = -bco[((dd * (15 - dd)) >> 1) + ee - dd - 1];
                    Cexp[cur ^ 1][cc][dd][ee] = cv;
                }
            } else {
                int lh = l & 31;
                int c2 = ((tid >> 6) - 6) * 2 + (l >> 5);
                int o = (lh >> 2) & 7, q2 = lh & 3;
                float acc = 0.f;
                #pragma unroll
                for (int i = 0; i < 4; ++i){
                    f32x4 wv = *(const f32x4*)&WrL[o * SS + q2 * 16 + i * 4];
                    f32x4 hv = *(const f32x4*)&hfb[c2][cur][q2 * 16 + i * 4];
                    acc += wv.x * hv.x + wv.y * hv.y + wv.z * hv.z + wv.w * hv.w;
                }
                acc += __shfl_xor(acc, 1); acc += __shfl_xor(acc, 2);
                if (q2 == 0) outC[c2][n & 31][o] = brL[o] + acc;
                if ((n & 31) == 31){
                    // flush: 1024 floats = 256 f32x4; 128 lanes x 2
                    int lid = (tid - 384);
                    #pragma unroll
                    for (int k = 0; k < 2; ++k){
                        int slot = lid * 2 + k;
                        int c = slot >> 6, rem = slot & 63;
                        size_t base = (size_t)(b0 + c) * (NWIN + 1) * OUTD + (size_t)(n - 31) * OUTD;
                        const f32x4* oc = (const f32x4*)&outC[c][0][0];
                        *(f32x4*)&out[base + rem * 4] = oc[rem];
                    }
                }
            }
        }
        __syncthreads();

        // ---- S7: t0 = s0' * (W0 @ u); 2 passes ----
        {
            #pragma unroll
            for (int p = 0; p < 2; ++p){
                f32x4 acc = zero4;
                acc = __builtin_amdgcn_mfma_f32_16x16x32_bf16(a0f[0], *(const short8v*)&Bp7[p][(0 * 64 + l) * 8], acc, 0, 0, 0);
                acc = __builtin_amdgcn_mfma_f32_16x16x32_bf16(a0f[1], *(const short8v*)&Bp7[p][(1 * 64 + l) * 8], acc, 0, 0, 0);
                int c = 2 * p + (ln >> 3);
                f32x4 sg = *(const f32x4*)&s0p[c][rb];
                uint2 pk; pk.x = pk2(sg[0] * acc[0], sg[1] * acc[1]);
                pk.y = pk2(sg[2] * acc[2], sg[3] * acc[3]);
                *(uint2*)&Bp8[p][BPOS(rb, ln)] = pk;
            }
        }
        __syncthreads();

        // ---- S8: q = s1' * (W1 @ t0); write Bp9 relabeled: img d>>2, col (d&3)*4+c ----
        {
            #pragma unroll
            for (int p = 0; p < 2; ++p){
                f32x4 acc = zero4;
                #pragma unroll
                for (int ks = 0; ks < 4; ++ks)
                    acc = __builtin_amdgcn_mfma_f32_16x16x32_bf16(a1f[ks], *(const short8v*)&Bp8[p][(ks * 64 + l) * 8], acc, 0, 0, 0);
                int c = 2 * p + (ln >> 3), d = ln & 7;
                f32x4 sg = *(const f32x4*)&s1p[c][rb];
                uint2 pk; pk.x = pk2(sg[0] * acc[0], sg[1] * acc[1]);
                pk.y = pk2(sg[2] * acc[2], sg[3] * acc[3]);
                *(uint2*)&Bp9[d >> 2][BPOS(rb, (d & 3) * 4 + c)] = pk;
            }
        }
        __syncthreads();

        // ---- S9': R + h-update merged (permuted rows; butterfly sum over d) ----
        {
            f32x4 accA[2][4];
            #pragma unroll
            for (int p = 0; p < 2; ++p){
                short8v bf[4];
                #pragma unroll
                for (int ks = 0; ks < 4; ++ks) bf[ks] = *(const short8v*)&Bp9[p][(ks * 64 + l) * 8];
                f32x4 t0a = zero4, t1a = zero4, t2a = zero4, t3a = zero4;
                #pragma unroll
                for (int ks = 0; ks < 4; ++ks){
                    t0a = __builtin_amdgcn_mfma_f32_16x16x32_bf16(a2p0[ks], bf[ks], t0a, 0, 0, 0);
                    t1a = __builtin_amdgcn_mfma_f32_16x16x32_bf16(a2p1[ks], bf[ks], t1a, 0, 0, 0);
                    t2a = __builtin_amdgcn_mfma_f32_16x16x32_bf16(a2p2[ks], bf[ks], t2a, 0, 0, 0);
                    t3a = __builtin_amdgcn_mfma_f32_16x16x32_bf16(a2p3[ks], bf[ks], t3a, 0, 0, 0);
                }
                accA[p][0] = t0a; accA[p][1] = t1a; accA[p][2] = t2a; accA[p][3] = t3a;
            }
            const int p  = lg & 1;
            const int rs = ln >> 2;
            const int c  = ln & 3;
            const int d  = p * 4 + rs;
            const int b  = lg >> 1;
            const float aval = sAll[c][n * DD + d];
            float P[4];
            #pragma unroll
            for (int t = 0; t < 4; ++t){
                int s = 8 * w + 2 * t + b;
                float v = Vl[c * CSTR + d * DSTR + s];
                float pre = accA[p][t][rs];
                P[t] = (1.f - v * v) * pre + aval * v;
            }
            #pragma unroll
            for (int t = 0; t < 4; ++t){
                P[t] += __shfl_xor(P[t], 4);
                P[t] += __shfl_xor(P[t], 8);
                P[t] += __shfl_xor(P[t], 16);
            }
            if (p == 0 && rs == 0){   // owner: ln = c (0..3), lg in {0,2}
                #pragma unroll
                for (int t = 0; t < 4; ++t){
                    int s = 8 * w + 2 * t + b;
                    float hN = hfb[c][cur][s] + P[t];
                    hfb[c][cur ^ 1][s] = hN;
                    BpH[BPOS(s, c)] = (short)f2bf(hN);
                }
            }
        }
        __syncthreads();
    }

    // final readout: h_NWIN in hfb[c][0] (NWIN even)
    if (tid >= 384){
        int lh = l & 31;
        int c2 = ((tid >> 6) - 6) * 2 + (l >> 5);
        int o = (lh >> 2) & 7, q2 = lh & 3;
        float acc = 0.f;
        #pragma unroll
        for (int i = 0; i < 4; ++i){
            f32x4 wv = *(const f32x4*)&WrL[o * SS + q2 * 16 + i * 4];
            f32x4 hv = *(const f32x4*)&hfb[c2][0][q2 * 16 + i * 4];
            acc += wv.x * hv.x + wv.y * hv.y + wv.z * hv.z + wv.w * hv.w;
        }
        acc += __shfl_xor(acc, 1); acc += __shfl_xor(acc, 2);
        if (q2 == 0)
            out[(size_t)(b0 + c2) * (NWIN + 1) * OUTD + (size_t)NWIN * OUTD + o] = brL[o] + acc;
    }
}

extern "C" void kernel_launch(void* const* d_in, const int* in_sizes, int n_in,
                              void* d_out, int out_size, void* d_ws, size_t ws_size,
                              hipStream_t stream){
    const float* x   = (const float*)d_in[1];
    const float* Wi0 = (const float*)d_in[2];
    const float* bi0 = (const float*)d_in[3];
    const float* Wi1 = (const float*)d_in[4];
    const float* bi1 = (const float*)d_in[5];
    const float* Wi2 = (const float*)d_in[6];
    const float* bi2 = (const float*)d_in[7];
    const float* Wv0 = (const float*)d_in[8];
    const float* bv0 = (const float*)d_in[9];
    const float* Wv1 = (const float*)d_in[10];
    const float* bv1 = (const float*)d_in[11];
    const float* Wv2 = (const float*)d_in[12];
    const float* bv2 = (const float*)d_in[13];
    const float* Wr  = (const float*)d_in[14];
    const float* br  = (const float*)d_in[15];
    float* out = (float*)d_out;

    float* s1w = (float*)d_ws;
    float* s2w = s1w + (size_t)BB * NWIN * DD;

    sig_kernel<<<(BB * NWIN + 255) / 256, 256, 0, stream>>>(x, s1w, s2w);
    scan_kernel<<<BB / 4, 512, 0, stream>>>(x, Wi0, bi0, Wi1, bi1, Wi2, bi2,
                                            Wv0, bv0, Wv1, bv1, Wv2, bv2,
                                            Wr, br, s1w, s2w, out);
}

// Round 17
// 519.859 us; speedup vs baseline: 1.8545x; 1.8545x over previous
//
#include <hip/hip_runtime.h>
#include <hip/hip_bf16.h>

#define DD 8
#define SS 64
#define HH 128
#define OUTD 8
#define TT 2049
#define BB 32
#define WINW 16
#define NWIN 128
#define PP 28
#define VSTR 516   // padded chain stride for Vl/Rf (shifts banks by 4 per chain)

typedef __attribute__((ext_vector_type(8))) short short8v;
typedef __attribute__((ext_vector_type(4))) float f32x4;

__device__ __forceinline__ float softplus_f(float x){
    return fmaxf(x, 0.f) + __logf(1.f + __expf(-fabsf(x)));
}
__device__ __forceinline__ float tanh_f(float x){
    float e = __expf(2.f * x);
    return 1.f - 2.f / (e + 1.f);
}
__device__ __forceinline__ void sp_sig(float x, float& sp, float& sg){
    float t = __expf(-fabsf(x));
    float r = 1.f / (1.f + t);
    sg = x > 0.f ? r : 1.f - r;
    sp = fmaxf(x, 0.f) - __logf(r);
}
__device__ __forceinline__ unsigned short f2bf(float f){
    return __builtin_bit_cast(unsigned short, __float2bfloat16(f));
}
__device__ __forceinline__ unsigned pk2(float a, float b){
    unsigned lo = (unsigned)__builtin_bit_cast(unsigned short, __float2bfloat16(a));
    unsigned hi = (unsigned)__builtin_bit_cast(unsigned short, __float2bfloat16(b));
    return lo | (hi << 16);
}

// ---------------- signatures: s1 (B,NWIN,D), s2 (B,NWIN,P) ----------------
__global__ void sig_kernel(const float* __restrict__ x,
                           float* __restrict__ s1o, float* __restrict__ s2o){
    int w = blockIdx.x * blockDim.x + threadIdx.x;
    if (w >= BB * NWIN) return;
    int b = w >> 7, n = w & (NWIN - 1);
    const float* xp = x + ((size_t)b * TT + (size_t)n * WINW) * DD;
    float prev[DD], cum[DD], s1v[DD], M[DD][DD];
    #pragma unroll
    for (int i = 0; i < DD; ++i){
        cum[i] = 0.f; s1v[i] = 0.f;
        #pragma unroll
        for (int j = 0; j < DD; ++j) M[i][j] = 0.f;
    }
    #pragma unroll
    for (int i = 0; i < DD; ++i) prev[i] = xp[i];
    for (int t = 0; t < WINW; ++t){
        float cur[DD], del[DD];
        #pragma unroll
        for (int i = 0; i < DD; ++i) cur[i] = xp[(t + 1) * DD + i];
        #pragma unroll
        for (int i = 0; i < DD; ++i) del[i] = cur[i] - prev[i];
        #pragma unroll
        for (int i = 0; i < DD; ++i){
            #pragma unroll
            for (int j = 0; j < DD; ++j) M[i][j] += cum[i] * del[j];
        }
        #pragma unroll
        for (int i = 0; i < DD; ++i){ cum[i] += del[i]; s1v[i] += del[i]; prev[i] = cur[i]; }
    }
    #pragma unroll
    for (int i = 0; i < DD; ++i) s1o[(size_t)w * DD + i] = s1v[i];
    int p = 0;
    #pragma unroll
    for (int i = 0; i < DD; ++i){
        #pragma unroll
        for (int j = i + 1; j < DD; ++j){ s2o[(size_t)w * PP + p] = 0.5f * (M[i][j] - M[j][i]); ++p; }
    }
}

// image position (shorts): k-row k, col nn of a [K/32][64][8] B-image
#define BPOS(k, nn) ((((k) >> 5) * 64 + (((k) >> 3) & 3) * 16 + (nn)) * 8 + ((k) & 7))

// ---------------- main scan: 4 chains per 512-thread block, 8 waves ----------------
__global__ __launch_bounds__(512, 2) void scan_kernel(
    const float* __restrict__ x,
    const float* __restrict__ Wi0, const float* __restrict__ bi0,
    const float* __restrict__ Wi1, const float* __restrict__ bi1,
    const float* __restrict__ Wi2, const float* __restrict__ bi2,
    const float* __restrict__ Wv0, const float* __restrict__ bv0,
    const float* __restrict__ Wv1, const float* __restrict__ bv1,
    const float* __restrict__ Wv2, const float* __restrict__ bv2,
    const float* __restrict__ Wr,  const float* __restrict__ br,
    const float* __restrict__ s1g, const float* __restrict__ s2g,
    float* __restrict__ out)
{
    const int tid = threadIdx.x;
    const int w   = tid >> 6;   // wave 0..7 (= m-tile / d-block)
    const int l   = tid & 63;
    const int lg  = l >> 4;
    const int ln  = l & 15;
    const int b0  = blockIdx.x * 4;

    __shared__ __align__(16) short BpH[2 * 64 * 8];       // h:  cols 0-3 = chains
    __shared__ __align__(16) short Bp0[4 * 64 * 8];       // z0: cols 0-3
    __shared__ __align__(16) short Bp1[4 * 64 * 8];       // z1: chain c -> cols 4c..4c+3 (dup)
    __shared__ __align__(16) short Bp7[2][2 * 64 * 8];    // u:  image c>>1, col (c&1)*8+d
    __shared__ __align__(16) short Bp8[2][4 * 64 * 8];    // t0: image p,    col (c&1)*8+d (c=2p+..)
    __shared__ __align__(16) short Bp9[2][4 * 64 * 8];    // q:  image d>>2, col (d&3)*4+c
    __shared__ __align__(16) float s0p[4][HH], s1p[4][HH];
    __shared__ __align__(16) float Vl[4 * VSTR], Rf[4 * VSTR];
    __shared__ __align__(16) float hfb[4][2][SS];
    __shared__ __align__(16) float bv0L[HH], bv1L[HH], bv2L[512];
    __shared__ __align__(16) float WrL[OUTD * SS];
    __shared__ float brL[OUTD];
    __shared__ __align__(16) float sAll[4][NWIN * DD];    // 16 KB
    __shared__ __align__(16) float bAll[4][NWIN * PP];    // 56 KB
    __shared__ __align__(16) float outC[4][32][OUTD];     // 4 KB output chunk
    __shared__ __align__(16) float Cexp[4][DD][12];       // expanded C, padded rows (48B)

    // -------- prologue: reg A-fragments, stage weights + coefficients --------
    short8v a0f[2], a1f[4];
    short8v a2f0[4], a2f1[4], a2f2[4], a2f3[4];
    #pragma unroll
    for (int ks = 0; ks < 2; ++ks){
        const float* p = Wv0 + (size_t)(w * 16 + ln) * SS + ks * 32 + lg * 8;
        short8v f;
        #pragma unroll
        for (int j = 0; j < 8; ++j) f[j] = (short)f2bf(p[j]);
        a0f[ks] = f;
    }
    #pragma unroll
    for (int ks = 0; ks < 4; ++ks){
        const float* p = Wv1 + (size_t)(w * 16 + ln) * HH + ks * 32 + lg * 8;
        short8v f;
        #pragma unroll
        for (int j = 0; j < 8; ++j) f[j] = (short)f2bf(p[j]);
        a1f[ks] = f;
    }
    #pragma unroll
    for (int ks = 0; ks < 4; ++ks){
        const float* p0 = Wv2 + (size_t)(64 * w + 0 * 16 + ln) * HH + ks * 32 + lg * 8;
        const float* p1 = Wv2 + (size_t)(64 * w + 1 * 16 + ln) * HH + ks * 32 + lg * 8;
        const float* p2 = Wv2 + (size_t)(64 * w + 2 * 16 + ln) * HH + ks * 32 + lg * 8;
        const float* p3 = Wv2 + (size_t)(64 * w + 3 * 16 + ln) * HH + ks * 32 + lg * 8;
        short8v f0, f1, f2, f3;
        #pragma unroll
        for (int j = 0; j < 8; ++j){
            f0[j] = (short)f2bf(p0[j]); f1[j] = (short)f2bf(p1[j]);
            f2[j] = (short)f2bf(p2[j]); f3[j] = (short)f2bf(p3[j]);
        }
        a2f0[ks] = f0; a2f1[ks] = f1; a2f2[ks] = f2; a2f3[ks] = f3;
    }
    if (tid < HH){ bv0L[tid] = bv0[tid]; bv1L[tid] = bv1[tid]; }
    bv2L[tid] = bv2[tid];
    WrL[tid]  = Wr[tid];
    if (tid < OUTD) brL[tid] = br[tid];
    {
        float* sF = &sAll[0][0];
        for (int i = tid; i < 4 * NWIN * DD; i += 512){
            int c = i >> 10;
            sF[i] = s1g[(size_t)(b0 + c) * (NWIN * DD) + (i & 1023)];
        }
        float* bF = &bAll[0][0];
        for (int i = tid; i < 4 * NWIN * PP; i += 512){
            int c = i / (NWIN * PP);
            bF[i] = s2g[(size_t)(b0 + c) * (NWIN * PP) + (i - c * (NWIN * PP))];
        }
        // zero pad columns of GEMV images once
        for (int i = tid; i < 2 * 64 * 8; i += 512) BpH[i] = 0;
        for (int i = tid; i < 4 * 64 * 8; i += 512){ Bp0[i] = 0; Bp1[i] = 0; }
    }
    __syncthreads();

    // -------- initial MLP (f32) for 4 chains + Cexp for step 0 --------
    {
        int c4 = tid >> 7, r = tid & 127;
        float acc = bi0[r];
        const float* x0 = x + (size_t)(b0 + c4) * TT * DD;
        #pragma unroll
        for (int k = 0; k < DD; ++k) acc += Wi0[r * DD + k] * x0[k];
        s0p[c4][r] = softplus_f(acc);
    }
    if (tid < 256){
        int cc = tid >> 6, dd = (tid >> 3) & 7, ee = tid & 7;
        const float* bco = &bAll[cc][0];
        float cv = 0.f;
        if (ee < dd)      cv =  bco[((ee * (15 - ee)) >> 1) + dd - ee - 1];
        else if (ee > dd) cv = -bco[((dd * (15 - dd)) >> 1) + ee - dd - 1];
        Cexp[cc][dd][ee] = cv;
    }
    __syncthreads();
    {
        int c4 = tid >> 7, r = tid & 127;
        float acc = bi1[r];
        const f32x4* wv = (const f32x4*)(Wi1 + (size_t)r * HH);
        const f32x4* zv = (const f32x4*)&s0p[c4][0];
        #pragma unroll 8
        for (int k = 0; k < 32; ++k){
            f32x4 a = wv[k], z = zv[k];
            acc += a.x * z.x + a.y * z.y + a.z * z.z + a.w * z.w;
        }
        s1p[c4][r] = softplus_f(acc);
    }
    __syncthreads();
    if (tid < 256){
        int c4 = tid >> 6, s = tid & 63;
        float acc = bi2[s];
        const f32x4* wv = (const f32x4*)(Wi2 + (size_t)s * HH);
        const f32x4* zv = (const f32x4*)&s1p[c4][0];
        #pragma unroll 8
        for (int k = 0; k < 32; ++k){
            f32x4 a = wv[k], z = zv[k];
            acc += a.x * z.x + a.y * z.y + a.z * z.z + a.w * z.w;
        }
        hfb[c4][0][s] = acc;
        BpH[BPOS(s, c4)] = (short)f2bf(acc);
    }
    __syncthreads();

    const f32x4 zero4 = {0.f, 0.f, 0.f, 0.f};
    const int rb = w * 16 + lg * 4;

    // -------- scan --------
    for (int n = 0; n < NWIN; ++n){
        // ---- S1: z0 = sp(W0 @ h), cols 0-3 = 4 chains ----
        {
            f32x4 acc = zero4;
            acc = __builtin_amdgcn_mfma_f32_16x16x32_bf16(a0f[0], *(const short8v*)&BpH[(0 * 64 + l) * 8], acc, 0, 0, 0);
            acc = __builtin_amdgcn_mfma_f32_16x16x32_bf16(a0f[1], *(const short8v*)&BpH[(1 * 64 + l) * 8], acc, 0, 0, 0);
            if (ln < 4){
                int c = ln;
                f32x4 bv = *(const f32x4*)&bv0L[rb];
                float z[4], sgv[4];
                #pragma unroll
                for (int r = 0; r < 4; ++r){
                    float zz, gg;
                    sp_sig(acc[r] + bv[r], zz, gg);
                    z[r] = zz; sgv[r] = gg;
                }
                f32x4 sg = {sgv[0], sgv[1], sgv[2], sgv[3]};
                *(f32x4*)&s0p[c][rb] = sg;
                uint2 pk; pk.x = pk2(z[0], z[1]); pk.y = pk2(z[2], z[3]);
                *(uint2*)&Bp0[BPOS(rb, c)] = pk;
            }
        }
        __syncthreads();

        // ---- S3: z1 = sp(W1 @ z0); chain c -> Bp1 cols 4c..4c+3 (dup) ----
        {
            f32x4 acc = zero4;
            #pragma unroll
            for (int ks = 0; ks < 4; ++ks)
                acc = __builtin_amdgcn_mfma_f32_16x16x32_bf16(a1f[ks], *(const short8v*)&Bp0[(ks * 64 + l) * 8], acc, 0, 0, 0);
            if (ln < 4){
                int c = ln;
                f32x4 bv = *(const f32x4*)&bv1L[rb];
                float z[4], sgv[4];
                #pragma unroll
                for (int r = 0; r < 4; ++r){
                    float zz, gg;
                    sp_sig(acc[r] + bv[r], zz, gg);
                    z[r] = zz; sgv[r] = gg;
                }
                f32x4 sg = {sgv[0], sgv[1], sgv[2], sgv[3]};
                *(f32x4*)&s1p[c][rb] = sg;
                uint2 pk; pk.x = pk2(z[0], z[1]); pk.y = pk2(z[2], z[3]);
                #pragma unroll
                for (int cc = 0; cc < 4; ++cc) *(uint2*)&Bp1[BPOS(rb, c * 4 + cc)] = pk;
            }
        }
        __syncthreads();

        // ---- S4: V_d = tanh(W2_d @ z1 + bv2), d = w; lanes: c=ln>>2, t=ln&3 ----
        {
            short8v bf[4];
            #pragma unroll
            for (int ks = 0; ks < 4; ++ks) bf[ks] = *(const short8v*)&Bp1[(ks * 64 + l) * 8];
            f32x4 acc0 = zero4, acc1 = zero4, acc2 = zero4, acc3 = zero4;
            #pragma unroll
            for (int ks = 0; ks < 4; ++ks){
                acc0 = __builtin_amdgcn_mfma_f32_16x16x32_bf16(a2f0[ks], bf[ks], acc0, 0, 0, 0);
                acc1 = __builtin_amdgcn_mfma_f32_16x16x32_bf16(a2f1[ks], bf[ks], acc1, 0, 0, 0);
                acc2 = __builtin_amdgcn_mfma_f32_16x16x32_bf16(a2f2[ks], bf[ks], acc2, 0, 0, 0);
                acc3 = __builtin_amdgcn_mfma_f32_16x16x32_bf16(a2f3[ks], bf[ks], acc3, 0, 0, 0);
            }
            {
                int c = ln >> 2, t = ln & 3;
                f32x4 av = (t == 0) ? acc0 : (t == 1) ? acc1 : (t == 2) ? acc2 : acc3;
                int r4 = 64 * w + t * 16 + lg * 4;
                f32x4 bv = *(const f32x4*)&bv2L[r4];
                f32x4 vv;
                #pragma unroll
                for (int r = 0; r < 4; ++r) vv[r] = tanh_f(av[r] + bv[r]);
                *(f32x4*)&Vl[c * VSTR + r4] = vv;
            }
        }
        __syncthreads();

        // ---- U: u[c][d] = sum_e Cexp[c][d][e] * V[c][e]; 512 thr, 4 s each ----
        {
            int c = tid >> 7, d = (tid >> 4) & 7, s0v = (tid & 15) * 4;
            f32x4 cm0 = *(const f32x4*)&Cexp[c][d][0];
            f32x4 cm1 = *(const f32x4*)&Cexp[c][d][4];
            f32x4 acc = zero4;
            #pragma unroll
            for (int e = 0; e < 8; ++e){
                float ce = (e < 4) ? cm0[e] : cm1[e - 4];
                f32x4 v4 = *(const f32x4*)&Vl[c * VSTR + e * 64 + s0v];
                acc.x += ce * v4.x; acc.y += ce * v4.y;
                acc.z += ce * v4.z; acc.w += ce * v4.w;
            }
            uint2 pk; pk.x = pk2(acc.x, acc.y); pk.y = pk2(acc.z, acc.w);
            *(uint2*)&Bp7[c >> 1][BPOS(s0v, (c & 1) * 8 + d)] = pk;
        }
        __syncthreads();

        // ---- S7: t0 = s0' * (W0 @ u); all 16 cols; write Bp8 (same col) ----
        {
            #pragma unroll
            for (int p = 0; p < 2; ++p){
                f32x4 acc = zero4;
                acc = __builtin_amdgcn_mfma_f32_16x16x32_bf16(a0f[0], *(const short8v*)&Bp7[p][(0 * 64 + l) * 8], acc, 0, 0, 0);
                acc = __builtin_amdgcn_mfma_f32_16x16x32_bf16(a0f[1], *(const short8v*)&Bp7[p][(1 * 64 + l) * 8], acc, 0, 0, 0);
                int c = 2 * p + (ln >> 3);
                f32x4 sg = *(const f32x4*)&s0p[c][rb];
                uint2 pk; pk.x = pk2(sg[0] * acc[0], sg[1] * acc[1]);
                pk.y = pk2(sg[2] * acc[2], sg[3] * acc[3]);
                *(uint2*)&Bp8[p][BPOS(rb, ln)] = pk;
            }
        }
        __syncthreads();

        // ---- S8: q = s1' * (W1 @ t0); write Bp9 relabeled: img d>>2, col (d&3)*4+c ----
        {
            #pragma unroll
            for (int p = 0; p < 2; ++p){
                f32x4 acc = zero4;
                #pragma unroll
                for (int ks = 0; ks < 4; ++ks)
                    acc = __builtin_amdgcn_mfma_f32_16x16x32_bf16(a1f[ks], *(const short8v*)&Bp8[p][(ks * 64 + l) * 8], acc, 0, 0, 0);
                int c = 2 * p + (ln >> 3), d = ln & 7;
                f32x4 sg = *(const f32x4*)&s1p[c][rb];
                uint2 pk; pk.x = pk2(sg[0] * acc[0], sg[1] * acc[1]);
                pk.y = pk2(sg[2] * acc[2], sg[3] * acc[3]);
                *(uint2*)&Bp9[d >> 2][BPOS(rb, (d & 3) * 4 + c)] = pk;
            }
        }
        __syncthreads();

        // ---- S9: R_d = (1-V^2) * (W2_d @ q[:,c,d]), d = w; ONE image (w>>2) ----
        {
            const int im = w >> 2;
            short8v bf[4];
            #pragma unroll
            for (int ks = 0; ks < 4; ++ks) bf[ks] = *(const short8v*)&Bp9[im][(ks * 64 + l) * 8];
            f32x4 acc0 = zero4, acc1 = zero4, acc2 = zero4, acc3 = zero4;
            #pragma unroll
            for (int ks = 0; ks < 4; ++ks){
                acc0 = __builtin_amdgcn_mfma_f32_16x16x32_bf16(a2f0[ks], bf[ks], acc0, 0, 0, 0);
                acc1 = __builtin_amdgcn_mfma_f32_16x16x32_bf16(a2f1[ks], bf[ks], acc1, 0, 0, 0);
                acc2 = __builtin_amdgcn_mfma_f32_16x16x32_bf16(a2f2[ks], bf[ks], acc2, 0, 0, 0);
                acc3 = __builtin_amdgcn_mfma_f32_16x16x32_bf16(a2f3[ks], bf[ks], acc3, 0, 0, 0);
            }
            if ((ln >> 2) == (w & 3)){
                int c = ln & 3;
                #pragma unroll
                for (int t = 0; t < 4; ++t){
                    f32x4 av = (t == 0) ? acc0 : (t == 1) ? acc1 : (t == 2) ? acc2 : acc3;
                    int r4 = 64 * w + t * 16 + lg * 4;
                    f32x4 vv = *(const f32x4*)&Vl[c * VSTR + r4];
                    f32x4 rr;
                    #pragma unroll
                    for (int r = 0; r < 4; ++r) rr[r] = (1.f - vv[r] * vv[r]) * av[r];
                    *(f32x4*)&Rf[c * VSTR + r4] = rr;
                }
            }
        }
        __syncthreads();

        // ---- upd: waves 0-3 h-update (c=w) | waves 4-7 readout + Cexp(n+1) + flush ----
        {
            const int cur = n & 1;
            if (w < 4){
                int c = w, s = l;
                f32x4 a0 = *(const f32x4*)&sAll[c][n * DD];
                f32x4 a1 = *(const f32x4*)&sAll[c][n * DD + 4];
                float hN = hfb[c][cur][s];
                #pragma unroll
                for (int d = 0; d < 4; ++d)
                    hN += a0[d] * Vl[c * VSTR + d * 64 + s] + Rf[c * VSTR + d * 64 + s];
                #pragma unroll
                for (int d = 4; d < 8; ++d)
                    hN += a1[d - 4] * Vl[c * VSTR + d * 64 + s] + Rf[c * VSTR + d * 64 + s];
                hfb[c][cur ^ 1][s] = hN;
                BpH[BPOS(s, c)] = (short)f2bf(hN);
            } else {
                // Cexp for step n+1
                {
                    int idx = (w - 4) * 64 + l;
                    int cc = idx >> 6, dd = (idx >> 3) & 7, ee = idx & 7;
                    int nn = (n + 1 < NWIN) ? n + 1 : NWIN - 1;
                    const float* bco = &bAll[cc][nn * PP];
                    float cv = 0.f;
                    if (ee < dd)      cv =  bco[((ee * (15 - ee)) >> 1) + dd - ee - 1];
                    else if (ee > dd) cv = -bco[((dd * (15 - dd)) >> 1) + ee - dd - 1];
                    Cexp[cc][dd][ee] = cv;
                }
                int c = w - 4;
                int o = l >> 3, qq = l & 7;
                f32x4 w0 = *(const f32x4*)&WrL[o * SS + qq * 8];
                f32x4 w1 = *(const f32x4*)&WrL[o * SS + qq * 8 + 4];
                f32x4 h0 = *(const f32x4*)&hfb[c][cur][qq * 8];
                f32x4 h1 = *(const f32x4*)&hfb[c][cur][qq * 8 + 4];
                float acc = w0.x*h0.x + w0.y*h0.y + w0.z*h0.z + w0.w*h0.w
                          + w1.x*h1.x + w1.y*h1.y + w1.z*h1.z + w1.w*h1.w;
                acc += __shfl_xor(acc, 1); acc += __shfl_xor(acc, 2); acc += __shfl_xor(acc, 4);
                if (qq == 0) outC[c][n & 31][o] = brL[o] + acc;
                if ((n & 31) == 31){
                    size_t base = (size_t)(b0 + c) * (NWIN + 1) * OUTD + (size_t)(n - 31) * OUTD;
                    const f32x4* oc = (const f32x4*)&outC[c][0][0];
                    f32x4 v = oc[l];
                    *(f32x4*)&out[base + l * 4] = v;
                }
            }
        }
        __syncthreads();
    }

    // final readout: h_NWIN in hfb[c][0] (NWIN even)
    if (w >= 4){
        int c = w - 4;
        int o = l >> 3, qq = l & 7;
        f32x4 w0 = *(const f32x4*)&WrL[o * SS + qq * 8];
        f32x4 w1 = *(const f32x4*)&WrL[o * SS + qq * 8 + 4];
        f32x4 h0 = *(const f32x4*)&hfb[c][0][qq * 8];
        f32x4 h1 = *(const f32x4*)&hfb[c][0][qq * 8 + 4];
        float acc = w0.x*h0.x + w0.y*h0.y + w0.z*h0.z + w0.w*h0.w
                  + w1.x*h1.x + w1.y*h1.y + w1.z*h1.z + w1.w*h1.w;
        acc += __shfl_xor(acc, 1); acc += __shfl_xor(acc, 2); acc += __shfl_xor(acc, 4);
        if (qq == 0)
            out[(size_t)(b0 + c) * (NWIN + 1) * OUTD + (size_t)NWIN * OUTD + o] = brL[o] + acc;
    }
}

extern "C" void kernel_launch(void* const* d_in, const int* in_sizes, int n_in,
                              void* d_out, int out_size, void* d_ws, size_t ws_size,
                              hipStream_t stream){
    const float* x   = (const float*)d_in[1];
    const float* Wi0 = (const float*)d_in[2];
    const float* bi0 = (const float*)d_in[3];
    const float* Wi1 = (const float*)d_in[4];
    const float* bi1 = (const float*)d_in[5];
    const float* Wi2 = (const float*)d_in[6];
    const float* bi2 = (const float*)d_in[7];
    const float* Wv0 = (const float*)d_in[8];
    const float* bv0 = (const float*)d_in[9];
    const float* Wv1 = (const float*)d_in[10];
    const float* bv1 = (const float*)d_in[11];
    const float* Wv2 = (const float*)d_in[12];
    const float* bv2 = (const float*)d_in[13];
    const float* Wr  = (const float*)d_in[14];
    const float* br  = (const float*)d_in[15];
    float* out = (float*)d_out;

    float* s1w = (float*)d_ws;
    float* s2w = s1w + (size_t)BB * NWIN * DD;

    sig_kernel<<<(BB * NWIN + 255) / 256, 256, 0, stream>>>(x, s1w, s2w);
    scan_kernel<<<BB / 4, 512, 0, stream>>>(x, Wi0, bi0, Wi1, bi1, Wi2, bi2,
                                            Wv0, bv0, Wv1, bv1, Wv2, bv2,
                                            Wr, br, s1w, s2w, out);
}